// Round 15
// baseline (245.658 us; speedup 1.0000x reference)
//
#include <hip/hip_runtime.h>

#define HIDDEN 16
// ---- 1024-bucket sorted-CSR path ----
#define CB 1024         // nodes per bucket (power of two)
#define CB_SHIFT 10
#define NCB_MAX 512     // LDS limit for hist/fill buckets
#define CHUNK 4096      // edges per block in hist/fill (R10-proven)
#define BT 1024
#define SUBP 8          // scatter sub-passes in k_sortC (dense 16KB write windows)
// ---- fallback (split) path ----
#define SPL 8

// ======================= sorted-CSR path =======================

// per-chunk per-bucket histogram -> hcT[bucket*nchunk + chunk]; NO global atomics
__global__ void k_hist(const int* __restrict__ dst, int e, int ncb, int nchunk,
                       unsigned int* __restrict__ hcT) {
    __shared__ unsigned int h[NCB_MAX];
    for (int i = threadIdx.x; i < ncb; i += blockDim.x) h[i] = 0u;
    __syncthreads();
    int start = blockIdx.x * CHUNK;
    int end = min(start + CHUNK, e);
    int i = start + threadIdx.x;
    for (; i + 3 * 256 < end; i += 4 * 256) {
        unsigned d0 = dst[i], d1 = dst[i + 256], d2 = dst[i + 512], d3 = dst[i + 768];
        atomicAdd(&h[d0 >> CB_SHIFT], 1u);
        atomicAdd(&h[d1 >> CB_SHIFT], 1u);
        atomicAdd(&h[d2 >> CB_SHIFT], 1u);
        atomicAdd(&h[d3 >> CB_SHIFT], 1u);
    }
    for (; i < end; i += 256)
        atomicAdd(&h[((unsigned)dst[i]) >> CB_SHIFT], 1u);
    __syncthreads();
    for (int j = threadIdx.x; j < ncb; j += blockDim.x)
        hcT[(size_t)j * nchunk + blockIdx.x] = h[j];
}

// one block per bucket: in-place exclusive scan of hcT row; total -> cntc[b]
__global__ void k_scanf(unsigned int* __restrict__ hcT,
                        unsigned int* __restrict__ cntc, int nchunk) {
    __shared__ unsigned int ts[256];
    __shared__ unsigned int carry;
    int b = blockIdx.x, t = threadIdx.x;
    if (t == 0) carry = 0u;
    __syncthreads();
    size_t row = (size_t)b * nchunk;
    for (int t0 = 0; t0 < nchunk; t0 += 256) {
        int i = t0 + t;
        unsigned int v = (i < nchunk) ? hcT[row + i] : 0u;
        ts[t] = v;
        __syncthreads();
        for (int off = 1; off < 256; off <<= 1) {
            unsigned int u = (t >= off) ? ts[t - off] : 0u;
            __syncthreads();
            ts[t] += u;
            __syncthreads();
        }
        if (i < nchunk) hcT[row + i] = carry + ts[t] - v;
        __syncthreads();
        if (t == 0) carry += ts[255];
        __syncthreads();
    }
    if (t == 0) cntc[b] = carry;
}

// scan bucket totals -> basec (+ sentinels); ncb <= 256
__global__ __launch_bounds__(256) void
k_scanb(const unsigned int* __restrict__ cntc, int ncb,
        unsigned int* __restrict__ basec,
        unsigned int* __restrict__ rowptr, int n, unsigned int e) {
    __shared__ unsigned int tsum[256];
    int t = threadIdx.x;
    unsigned int s = (t < ncb) ? cntc[t] : 0u;
    tsum[t] = s;
    __syncthreads();
    for (int off = 1; off < 256; off <<= 1) {
        unsigned int v = (t >= off) ? tsum[t - off] : 0u;
        __syncthreads();
        tsum[t] += v;
        __syncthreads();
    }
    if (t < ncb) basec[t] = tsum[t] - s;
    if (t == 255) basec[ncb] = tsum[255];        // == e
    if (t == 0) rowptr[n] = e;                   // CSR sentinel
}

// scatter records (src<<10 | dst_local) using precomputed bases
__global__ void k_fill(const int* __restrict__ src, const int* __restrict__ dst,
                       int e, int ncb, int nchunk,
                       const unsigned int* __restrict__ basec,
                       const unsigned int* __restrict__ hcT,
                       unsigned int* __restrict__ tmp) {
    __shared__ unsigned int h[NCB_MAX];
    __shared__ unsigned int lb[NCB_MAX];
    for (int j = threadIdx.x; j < ncb; j += blockDim.x) {
        lb[j] = basec[j] + hcT[(size_t)j * nchunk + blockIdx.x];
        h[j] = 0u;
    }
    __syncthreads();
    int start = blockIdx.x * CHUNK;
    int end = min(start + CHUNK, e);
    for (int i = start + threadIdx.x; i < end; i += 256) {
        unsigned int d = (unsigned)dst[i];
        unsigned int s = (unsigned)src[i];
        unsigned int b = d >> CB_SHIFT;
        unsigned int r = atomicAdd(&h[b], 1u);
        tmp[lb[b] + r] = (s << CB_SHIFT) | (d & (CB - 1u));
    }
}

// FUSED per-bucket counting sort. Pass B is split into SUBP sub-passes over
// node sub-ranges so each sub-pass writes a dense ~16KB window (lines complete
// before eviction -> ~1x write amplification; R14 measured 4x without this).
__global__ __launch_bounds__(BT) void
k_sortC(const unsigned int* __restrict__ tmp,
        const unsigned int* __restrict__ basec,
        const float* __restrict__ x,
        unsigned int* __restrict__ rowptr, unsigned int* __restrict__ tmp2,
        float4* __restrict__ xs4, int n) {
    __shared__ unsigned int cnt[CB];
    __shared__ unsigned int sc[CB];
    __shared__ unsigned int cur[CB];
    int t = threadIdx.x, b = blockIdx.x;
    unsigned int s = basec[b], endp = basec[b + 1];
    cnt[t] = 0u;
    __syncthreads();
    for (unsigned int i = s + t; i < endp; i += BT)        // pass A: count
        atomicAdd(&cnt[tmp[i] & (CB - 1u)], 1u);
    __syncthreads();
    sc[t] = cnt[t];
    __syncthreads();
    for (int off = 1; off < CB; off <<= 1) {               // inclusive scan
        unsigned int v = (t >= off) ? sc[t - off] : 0u;
        __syncthreads();
        sc[t] += v;
        __syncthreads();
    }
    unsigned int excl = sc[t] - cnt[t];
    cur[t] = s + excl;
    int node = (b << CB_SHIFT) + t;
    if (node < n) {
        rowptr[node] = s + excl;
        float iv = rsqrtf((float)(1u + cnt[t]));           // +1 self-loop
        xs4[node] = make_float4(x[3 * node] * iv, x[3 * node + 1] * iv,
                                x[3 * node + 2] * iv, iv);
    }
    __syncthreads();
    // pass B: SUBP sub-passes; disjoint cur entries -> no barriers needed
#pragma unroll
    for (int p = 0; p < SUBP; p++) {
        unsigned int lo = p * (CB / SUBP);
        unsigned int hi = lo + (CB / SUBP);
        for (unsigned int i = s + t; i < endp; i += BT) {
            unsigned int rec = tmp[i];                     // L2-hot re-read
            unsigned int dl = rec & (CB - 1u);
            if (dl >= lo && dl < hi) {
                unsigned int r = atomicAdd(&cur[dl], 1u);
                tmp2[r] = rec >> CB_SHIFT;                 // dense 16KB window
            }
        }
    }
}

// layer-1: two threads per node, pair-combine via shfl_xor, fused epilogue
__global__ void k_s1(const unsigned int* __restrict__ rowptr,
                     const unsigned int* __restrict__ tmp2,
                     const float4* __restrict__ xs4,
                     const float* __restrict__ W1, const float* __restrict__ b1,
                     const float* __restrict__ W2, const float* __restrict__ b2,
                     float* __restrict__ t2s, float* __restrict__ out, int n) {
    int gid = blockIdx.x * blockDim.x + threadIdx.x;
    int i = gid >> 1, h = gid & 1;
    bool valid = (i < n);
    unsigned int s = 0, epos = 0;
    if (valid) { s = rowptr[i]; epos = rowptr[i + 1]; }
    unsigned int half = (epos - s) >> 1;
    unsigned int b0 = h ? s + half : s;
    unsigned int b1r = h ? epos : s + half;
    float v0 = 0.f, v1 = 0.f, v2 = 0.f;
    unsigned int j = b0;
    for (; j + 4 <= b1r; j += 4) {
        unsigned a0 = tmp2[j], a1 = tmp2[j + 1], a2 = tmp2[j + 2], a3 = tmp2[j + 3];
        float4 p0 = xs4[a0], p1 = xs4[a1], p2 = xs4[a2], p3 = xs4[a3];
        v0 += (p0.x + p1.x) + (p2.x + p3.x);
        v1 += (p0.y + p1.y) + (p2.y + p3.y);
        v2 += (p0.z + p1.z) + (p2.z + p3.z);
    }
    for (; j < b1r; j++) {
        float4 p = xs4[tmp2[j]];
        v0 += p.x; v1 += p.y; v2 += p.z;
    }
    v0 += __shfl_xor(v0, 1);
    v1 += __shfl_xor(v1, 1);
    v2 += __shfl_xor(v2, 1);
    if (valid && h == 0) {
        float4 me = xs4[i];
        float iv = me.w;
        v0 = (v0 + me.x) * iv;
        v1 = (v1 + me.y) * iv;
        v2 = (v2 + me.z) * iv;
        float acc = 0.f;
#pragma unroll
        for (int k = 0; k < HIDDEN; k++) {
            float hh = fmaxf(fmaf(v0, W1[k], fmaf(v1, W1[HIDDEN + k],
                            fmaf(v2, W1[2 * HIDDEN + k], b1[k]))), 0.f);
            acc += hh * W2[k];
        }
        t2s[i] = acc * iv;
        out[i] = b2[0] + acc * iv * iv;
    }
}

// layer-2: two threads per node, scalar gathers of t2s, pair-combine
__global__ void k_s2(const unsigned int* __restrict__ rowptr,
                     const unsigned int* __restrict__ tmp2,
                     const float* __restrict__ t2s, const float4* __restrict__ xs4,
                     float* __restrict__ out, int n) {
    int gid = blockIdx.x * blockDim.x + threadIdx.x;
    int i = gid >> 1, h = gid & 1;
    bool valid = (i < n);
    unsigned int s = 0, epos = 0;
    if (valid) { s = rowptr[i]; epos = rowptr[i + 1]; }
    unsigned int half = (epos - s) >> 1;
    unsigned int b0 = h ? s + half : s;
    unsigned int b1r = h ? epos : s + half;
    float v = 0.f;
    unsigned int j = b0;
    for (; j + 4 <= b1r; j += 4) {
        unsigned a0 = tmp2[j], a1 = tmp2[j + 1], a2 = tmp2[j + 2], a3 = tmp2[j + 3];
        v += (t2s[a0] + t2s[a1]) + (t2s[a2] + t2s[a3]);
    }
    for (; j < b1r; j++) v += t2s[tmp2[j]];
    v += __shfl_xor(v, 1);
    if (valid && h == 0) out[i] += v * xs4[i].w;
}

// ======================= split fallback backend (R10-proven) =======================

__global__ void k_zero(unsigned int* a, int na) {
    int i = blockIdx.x * blockDim.x + threadIdx.x;
    if (i < na) a[i] = 0u;
}
__global__ __launch_bounds__(BT) void
k_deg_split(const unsigned int* __restrict__ tmp, const unsigned int* __restrict__ basec,
            const unsigned int* __restrict__ cntc, unsigned int* __restrict__ deg, int n) {
    __shared__ unsigned int degl[CB];
    int t = threadIdx.x;
    degl[t] = 0u;
    __syncthreads();
    int b = blockIdx.x / SPL, sl = blockIdx.x % SPL;
    unsigned int s = basec[b], m = cntc[b];
    for (unsigned int i = sl * BT + t; i < m; i += SPL * BT)
        atomicAdd(&degl[tmp[s + i] & (CB - 1u)], 1u);
    __syncthreads();
    int node = b * CB + t;
    unsigned int c = degl[t];
    if (node < n && c) atomicAdd(&deg[node], c);
}
__global__ void k_inv_s(const unsigned int* __restrict__ deg, const float* __restrict__ x,
                        float4* __restrict__ xs4, int n) {
    int i = blockIdx.x * blockDim.x + threadIdx.x;
    if (i >= n) return;
    float iv = rsqrtf((float)(deg[i] + 1u));
    xs4[i] = make_float4(x[3 * i] * iv, x[3 * i + 1] * iv, x[3 * i + 2] * iv, iv);
}
__global__ __launch_bounds__(BT) void
k_s1_split(const unsigned int* __restrict__ tmp, const unsigned int* __restrict__ basec,
           const unsigned int* __restrict__ cntc, const float4* __restrict__ xs4,
           float* __restrict__ agg0, float* __restrict__ agg1, float* __restrict__ agg2, int n) {
    __shared__ float a0[CB], a1[CB], a2[CB];
    int t = threadIdx.x;
    a0[t] = 0.f; a1[t] = 0.f; a2[t] = 0.f;
    __syncthreads();
    int b = blockIdx.x / SPL, sl = blockIdx.x % SPL;
    unsigned int s = basec[b], m = cntc[b];
    for (unsigned int i = sl * BT + t; i < m; i += SPL * BT) {
        unsigned rec = tmp[s + i];
        float4 v = xs4[rec >> CB_SHIFT];
        unsigned dl = rec & (CB - 1u);
        atomicAdd(&a0[dl], v.x); atomicAdd(&a1[dl], v.y); atomicAdd(&a2[dl], v.z);
    }
    __syncthreads();
    int node = b * CB + t;
    if (node < n) {
        if (a0[t] != 0.f) atomicAdd(&agg0[node], a0[t]);
        if (a1[t] != 0.f) atomicAdd(&agg1[node], a1[t]);
        if (a2[t] != 0.f) atomicAdd(&agg2[node], a2[t]);
    }
}
__global__ void k_epi_s(const float* __restrict__ agg0, const float* __restrict__ agg1,
                        const float* __restrict__ agg2, const float4* __restrict__ xs4,
                        const float* __restrict__ W1, const float* __restrict__ b1,
                        const float* __restrict__ W2, const float* __restrict__ b2,
                        float* __restrict__ t2s, float* __restrict__ out, int n) {
    int i = blockIdx.x * blockDim.x + threadIdx.x;
    if (i >= n) return;
    float4 xv = xs4[i];
    float iv = xv.w;
    float v0 = iv * (agg0[i] + xv.x), v1 = iv * (agg1[i] + xv.y), v2 = iv * (agg2[i] + xv.z);
    float acc = 0.f;
#pragma unroll
    for (int j = 0; j < HIDDEN; j++) {
        float h = fmaxf(fmaf(v0, W1[j], fmaf(v1, W1[HIDDEN + j],
                       fmaf(v2, W1[2 * HIDDEN + j], b1[j]))), 0.f);
        acc += h * W2[j];
    }
    t2s[i] = acc * iv;
    out[i] = b2[0] + acc * iv * iv;
}
__global__ __launch_bounds__(BT) void
k_s2_split(const unsigned int* __restrict__ tmp, const unsigned int* __restrict__ basec,
           const unsigned int* __restrict__ cntc, const float* __restrict__ t2s,
           const float4* __restrict__ xs4, float* __restrict__ out, int n) {
    __shared__ float o[CB];
    int t = threadIdx.x;
    o[t] = 0.f;
    __syncthreads();
    int b = blockIdx.x / SPL, sl = blockIdx.x % SPL;
    unsigned int s = basec[b], m = cntc[b];
    for (unsigned int i = sl * BT + t; i < m; i += SPL * BT) {
        unsigned rec = tmp[s + i];
        atomicAdd(&o[rec & (CB - 1u)], t2s[rec >> CB_SHIFT]);
    }
    __syncthreads();
    int node = b * CB + t;
    if (node < n && o[t] != 0.f) atomicAdd(&out[node], o[t] * xs4[node].w);
}

// ======================= launch =======================

extern "C" void kernel_launch(void* const* d_in, const int* in_sizes, int n_in,
                              void* d_out, int out_size, void* d_ws, size_t ws_size,
                              hipStream_t stream) {
    const float* x  = (const float*)d_in[0];
    const int*   ei = (const int*)d_in[1];
    const float* W1 = (const float*)d_in[2];
    const float* b1 = (const float*)d_in[3];
    const float* W2 = (const float*)d_in[4];
    const float* b2 = (const float*)d_in[5];
    float* out = (float*)d_out;

    int n = in_sizes[0] / 3;
    int e = in_sizes[1] / 2;
    const int* src = ei;
    const int* dst = ei + e;
    const int B = 256;

    int ncb = (n + CB - 1) / CB;
    int nchunk = (e + CHUNK - 1) / CHUNK;
    int gridN2 = (2 * n + B - 1) / B;

    size_t needc = (size_t)n * 16 + (size_t)n * 4 + (size_t)(n + 1) * 4
                 + (size_t)(2 * ncb + 1) * 4 + (size_t)ncb * nchunk * 4
                 + (size_t)e * 8 + 64;

    if (ncb <= 256 && n < (1 << 21) && ws_size >= needc) {
        float4* xs4 = (float4*)d_ws;                            // n
        float* t2s = (float*)(xs4 + n);                         // n
        unsigned int* rowptr = (unsigned int*)(t2s + n);        // n+1
        unsigned int* cntc   = rowptr + (n + 1);                // ncb
        unsigned int* basec  = cntc + ncb;                      // ncb+1
        unsigned int* hcT    = basec + ncb + 1;                 // ncb*nchunk
        unsigned int* tmp    = hcT + (size_t)ncb * nchunk;      // e
        unsigned int* tmp2   = tmp + e;                         // e

        k_hist<<<nchunk, B, 0, stream>>>(dst, e, ncb, nchunk, hcT);
        k_scanf<<<ncb, B, 0, stream>>>(hcT, cntc, nchunk);
        k_scanb<<<1, B, 0, stream>>>(cntc, ncb, basec, rowptr, n, (unsigned)e);
        k_fill<<<nchunk, B, 0, stream>>>(src, dst, e, ncb, nchunk, basec, hcT, tmp);
        k_sortC<<<ncb, BT, 0, stream>>>(tmp, basec, x, rowptr, tmp2, xs4, n);
        k_s1<<<gridN2, B, 0, stream>>>(rowptr, tmp2, xs4, W1, b1, W2, b2, t2s, out, n);
        k_s2<<<gridN2, B, 0, stream>>>(rowptr, tmp2, t2s, xs4, out, n);
    } else {
        int gridN = (n + B - 1) / B;
        float4* xs4 = (float4*)d_ws;
        float* agg0 = (float*)(xs4 + n);
        float* agg1 = agg0 + n;
        float* agg2 = agg1 + n;
        unsigned int* deg = (unsigned int*)(agg2 + n);
        float* t2s = (float*)(deg + n);
        unsigned int* cntc   = (unsigned int*)(t2s + n);
        unsigned int* basec  = cntc + ncb;
        unsigned int* hcT    = basec + ncb + 1;
        unsigned int* tmp    = hcT + (size_t)ncb * nchunk;

        k_zero<<<(4 * n + B - 1) / B, B, 0, stream>>>((unsigned int*)agg0, 4 * n);
        k_hist<<<nchunk, B, 0, stream>>>(dst, e, ncb, nchunk, hcT);
        k_scanf<<<ncb, B, 0, stream>>>(hcT, cntc, nchunk);
        k_scanb<<<1, B, 0, stream>>>(cntc, ncb, basec, (unsigned int*)t2s, 0, (unsigned)e);
        k_fill<<<nchunk, B, 0, stream>>>(src, dst, e, ncb, nchunk, basec, hcT, tmp);
        k_deg_split<<<ncb * SPL, BT, 0, stream>>>(tmp, basec, cntc, deg, n);
        k_inv_s<<<gridN, B, 0, stream>>>(deg, x, xs4, n);
        k_s1_split<<<ncb * SPL, BT, 0, stream>>>(tmp, basec, cntc, xs4, agg0, agg1, agg2, n);
        k_epi_s<<<gridN, B, 0, stream>>>(agg0, agg1, agg2, xs4, W1, b1, W2, b2, t2s, out, n);
        k_s2_split<<<ncb * SPL, BT, 0, stream>>>(tmp, basec, cntc, t2s, xs4, out, n);
    }
}

// Round 16
// 196.719 us; speedup vs baseline: 1.2488x; 1.2488x over previous
//
#include <hip/hip_runtime.h>

#define HIDDEN 16
// ---- 1024-bucket sorted-CSR path ----
#define CB 1024         // nodes per bucket (power of two)
#define CB_SHIFT 10
#define NCB_MAX 512     // LDS limit for hist/fill buckets
#define CHUNK 4096      // edges per block in hist/fill (R10-proven)
#define BT 1024
#define SUBP 8          // parallel scatter sub-range blocks per bucket
#define SUBW (CB / SUBP)
// ---- fallback (split) path ----
#define SPL 8

// ======================= sorted-CSR path =======================

// per-chunk per-bucket histogram -> hcT[bucket*nchunk + chunk]; NO global atomics
__global__ void k_hist(const int* __restrict__ dst, int e, int ncb, int nchunk,
                       unsigned int* __restrict__ hcT) {
    __shared__ unsigned int h[NCB_MAX];
    for (int i = threadIdx.x; i < ncb; i += blockDim.x) h[i] = 0u;
    __syncthreads();
    int start = blockIdx.x * CHUNK;
    int end = min(start + CHUNK, e);
    int i = start + threadIdx.x;
    for (; i + 3 * 256 < end; i += 4 * 256) {
        unsigned d0 = dst[i], d1 = dst[i + 256], d2 = dst[i + 512], d3 = dst[i + 768];
        atomicAdd(&h[d0 >> CB_SHIFT], 1u);
        atomicAdd(&h[d1 >> CB_SHIFT], 1u);
        atomicAdd(&h[d2 >> CB_SHIFT], 1u);
        atomicAdd(&h[d3 >> CB_SHIFT], 1u);
    }
    for (; i < end; i += 256)
        atomicAdd(&h[((unsigned)dst[i]) >> CB_SHIFT], 1u);
    __syncthreads();
    for (int j = threadIdx.x; j < ncb; j += blockDim.x)
        hcT[(size_t)j * nchunk + blockIdx.x] = h[j];
}

// one block per bucket: in-place exclusive scan of hcT row; total -> cntc[b]
__global__ void k_scanf(unsigned int* __restrict__ hcT,
                        unsigned int* __restrict__ cntc, int nchunk) {
    __shared__ unsigned int ts[256];
    __shared__ unsigned int carry;
    int b = blockIdx.x, t = threadIdx.x;
    if (t == 0) carry = 0u;
    __syncthreads();
    size_t row = (size_t)b * nchunk;
    for (int t0 = 0; t0 < nchunk; t0 += 256) {
        int i = t0 + t;
        unsigned int v = (i < nchunk) ? hcT[row + i] : 0u;
        ts[t] = v;
        __syncthreads();
        for (int off = 1; off < 256; off <<= 1) {
            unsigned int u = (t >= off) ? ts[t - off] : 0u;
            __syncthreads();
            ts[t] += u;
            __syncthreads();
        }
        if (i < nchunk) hcT[row + i] = carry + ts[t] - v;
        __syncthreads();
        if (t == 0) carry += ts[255];
        __syncthreads();
    }
    if (t == 0) cntc[b] = carry;
}

// scan bucket totals -> basec (+ sentinels); ncb <= 256
__global__ __launch_bounds__(256) void
k_scanb(const unsigned int* __restrict__ cntc, int ncb,
        unsigned int* __restrict__ basec,
        unsigned int* __restrict__ rowptr, int n, unsigned int e) {
    __shared__ unsigned int tsum[256];
    int t = threadIdx.x;
    unsigned int s = (t < ncb) ? cntc[t] : 0u;
    tsum[t] = s;
    __syncthreads();
    for (int off = 1; off < 256; off <<= 1) {
        unsigned int v = (t >= off) ? tsum[t - off] : 0u;
        __syncthreads();
        tsum[t] += v;
        __syncthreads();
    }
    if (t < ncb) basec[t] = tsum[t] - s;
    if (t == 255) basec[ncb] = tsum[255];        // == e
    if (t == 0) rowptr[n] = e;                   // CSR sentinel
}

// scatter records (src<<10 | dst_local) using precomputed bases
__global__ void k_fill(const int* __restrict__ src, const int* __restrict__ dst,
                       int e, int ncb, int nchunk,
                       const unsigned int* __restrict__ basec,
                       const unsigned int* __restrict__ hcT,
                       unsigned int* __restrict__ tmp) {
    __shared__ unsigned int h[NCB_MAX];
    __shared__ unsigned int lb[NCB_MAX];
    for (int j = threadIdx.x; j < ncb; j += blockDim.x) {
        lb[j] = basec[j] + hcT[(size_t)j * nchunk + blockIdx.x];
        h[j] = 0u;
    }
    __syncthreads();
    int start = blockIdx.x * CHUNK;
    int end = min(start + CHUNK, e);
    for (int i = start + threadIdx.x; i < end; i += 256) {
        unsigned int d = (unsigned)dst[i];
        unsigned int s = (unsigned)src[i];
        unsigned int b = d >> CB_SHIFT;
        unsigned int r = atomicAdd(&h[b], 1u);
        tmp[lb[b] + r] = (s << CB_SHIFT) | (d & (CB - 1u));
    }
}

// per-bucket count + scan -> rowptr + xs4 (ONE pass; scatter moved to k_scat)
__global__ __launch_bounds__(BT) void
k_cnt(const unsigned int* __restrict__ tmp,
      const unsigned int* __restrict__ basec,
      const float* __restrict__ x,
      unsigned int* __restrict__ rowptr, float4* __restrict__ xs4, int n) {
    __shared__ unsigned int cnt[CB];
    __shared__ unsigned int sc[CB];
    int t = threadIdx.x, b = blockIdx.x;
    unsigned int s = basec[b], endp = basec[b + 1];
    cnt[t] = 0u;
    __syncthreads();
    for (unsigned int i = s + t; i < endp; i += BT)
        atomicAdd(&cnt[tmp[i] & (CB - 1u)], 1u);
    __syncthreads();
    sc[t] = cnt[t];
    __syncthreads();
    for (int off = 1; off < CB; off <<= 1) {               // inclusive scan
        unsigned int v = (t >= off) ? sc[t - off] : 0u;
        __syncthreads();
        sc[t] += v;
        __syncthreads();
    }
    int node = (b << CB_SHIFT) + t;
    if (node < n) {
        rowptr[node] = s + sc[t] - cnt[t];
        float iv = rsqrtf((float)(1u + cnt[t]));           // +1 self-loop
        xs4[node] = make_float4(x[3 * node] * iv, x[3 * node + 1] * iv,
                                x[3 * node + 2] * iv, iv);
    }
}

// parallel scatter: block (b,p) owns node sub-range [p*128,(p+1)*128) of
// bucket b. Cursors come straight from rowptr (no re-count); ONE pass over
// the bucket segment; writes land in a dense 16KB window (~1x write amp).
__global__ __launch_bounds__(BT) void
k_scat(const unsigned int* __restrict__ tmp,
       const unsigned int* __restrict__ basec,
       const unsigned int* __restrict__ rowptr,
       unsigned int* __restrict__ tmp2, int n) {
    __shared__ unsigned int cur[SUBW];
    int t = threadIdx.x;
    int b = blockIdx.x / SUBP, p = blockIdx.x % SUBP;
    unsigned int lo = p * SUBW;
    if (t < SUBW) {
        int node = (b << CB_SHIFT) + lo + t;
        cur[t] = (node < n) ? rowptr[node] : 0u;
    }
    __syncthreads();
    unsigned int s = basec[b], endp = basec[b + 1];
    for (unsigned int i = s + t; i < endp; i += BT) {
        unsigned int rec = tmp[i];                         // L2-hot re-read
        unsigned int dl = rec & (CB - 1u);
        if (dl - lo < SUBW) {
            unsigned int r = atomicAdd(&cur[dl - lo], 1u);
            tmp2[r] = rec >> CB_SHIFT;
        }
    }
}

// layer-1: two threads per node, pair-combine via shfl_xor, fused epilogue
__global__ void k_s1(const unsigned int* __restrict__ rowptr,
                     const unsigned int* __restrict__ tmp2,
                     const float4* __restrict__ xs4,
                     const float* __restrict__ W1, const float* __restrict__ b1,
                     const float* __restrict__ W2, const float* __restrict__ b2,
                     float* __restrict__ t2s, float* __restrict__ out, int n) {
    int gid = blockIdx.x * blockDim.x + threadIdx.x;
    int i = gid >> 1, h = gid & 1;
    bool valid = (i < n);
    unsigned int s = 0, epos = 0;
    if (valid) { s = rowptr[i]; epos = rowptr[i + 1]; }
    unsigned int half = (epos - s) >> 1;
    unsigned int b0 = h ? s + half : s;
    unsigned int b1r = h ? epos : s + half;
    float v0 = 0.f, v1 = 0.f, v2 = 0.f;
    unsigned int j = b0;
    for (; j + 4 <= b1r; j += 4) {
        unsigned a0 = tmp2[j], a1 = tmp2[j + 1], a2 = tmp2[j + 2], a3 = tmp2[j + 3];
        float4 p0 = xs4[a0], p1 = xs4[a1], p2 = xs4[a2], p3 = xs4[a3];
        v0 += (p0.x + p1.x) + (p2.x + p3.x);
        v1 += (p0.y + p1.y) + (p2.y + p3.y);
        v2 += (p0.z + p1.z) + (p2.z + p3.z);
    }
    for (; j < b1r; j++) {
        float4 p = xs4[tmp2[j]];
        v0 += p.x; v1 += p.y; v2 += p.z;
    }
    v0 += __shfl_xor(v0, 1);
    v1 += __shfl_xor(v1, 1);
    v2 += __shfl_xor(v2, 1);
    if (valid && h == 0) {
        float4 me = xs4[i];
        float iv = me.w;
        v0 = (v0 + me.x) * iv;
        v1 = (v1 + me.y) * iv;
        v2 = (v2 + me.z) * iv;
        float acc = 0.f;
#pragma unroll
        for (int k = 0; k < HIDDEN; k++) {
            float hh = fmaxf(fmaf(v0, W1[k], fmaf(v1, W1[HIDDEN + k],
                            fmaf(v2, W1[2 * HIDDEN + k], b1[k]))), 0.f);
            acc += hh * W2[k];
        }
        t2s[i] = acc * iv;
        out[i] = b2[0] + acc * iv * iv;
    }
}

// layer-2: two threads per node, scalar gathers of t2s, pair-combine
__global__ void k_s2(const unsigned int* __restrict__ rowptr,
                     const unsigned int* __restrict__ tmp2,
                     const float* __restrict__ t2s, const float4* __restrict__ xs4,
                     float* __restrict__ out, int n) {
    int gid = blockIdx.x * blockDim.x + threadIdx.x;
    int i = gid >> 1, h = gid & 1;
    bool valid = (i < n);
    unsigned int s = 0, epos = 0;
    if (valid) { s = rowptr[i]; epos = rowptr[i + 1]; }
    unsigned int half = (epos - s) >> 1;
    unsigned int b0 = h ? s + half : s;
    unsigned int b1r = h ? epos : s + half;
    float v = 0.f;
    unsigned int j = b0;
    for (; j + 4 <= b1r; j += 4) {
        unsigned a0 = tmp2[j], a1 = tmp2[j + 1], a2 = tmp2[j + 2], a3 = tmp2[j + 3];
        v += (t2s[a0] + t2s[a1]) + (t2s[a2] + t2s[a3]);
    }
    for (; j < b1r; j++) v += t2s[tmp2[j]];
    v += __shfl_xor(v, 1);
    if (valid && h == 0) out[i] += v * xs4[i].w;
}

// ======================= split fallback backend (R10-proven) =======================

__global__ void k_zero(unsigned int* a, int na) {
    int i = blockIdx.x * blockDim.x + threadIdx.x;
    if (i < na) a[i] = 0u;
}
__global__ __launch_bounds__(BT) void
k_deg_split(const unsigned int* __restrict__ tmp, const unsigned int* __restrict__ basec,
            const unsigned int* __restrict__ cntc, unsigned int* __restrict__ deg, int n) {
    __shared__ unsigned int degl[CB];
    int t = threadIdx.x;
    degl[t] = 0u;
    __syncthreads();
    int b = blockIdx.x / SPL, sl = blockIdx.x % SPL;
    unsigned int s = basec[b], m = cntc[b];
    for (unsigned int i = sl * BT + t; i < m; i += SPL * BT)
        atomicAdd(&degl[tmp[s + i] & (CB - 1u)], 1u);
    __syncthreads();
    int node = b * CB + t;
    unsigned int c = degl[t];
    if (node < n && c) atomicAdd(&deg[node], c);
}
__global__ void k_inv_s(const unsigned int* __restrict__ deg, const float* __restrict__ x,
                        float4* __restrict__ xs4, int n) {
    int i = blockIdx.x * blockDim.x + threadIdx.x;
    if (i >= n) return;
    float iv = rsqrtf((float)(deg[i] + 1u));
    xs4[i] = make_float4(x[3 * i] * iv, x[3 * i + 1] * iv, x[3 * i + 2] * iv, iv);
}
__global__ __launch_bounds__(BT) void
k_s1_split(const unsigned int* __restrict__ tmp, const unsigned int* __restrict__ basec,
           const unsigned int* __restrict__ cntc, const float4* __restrict__ xs4,
           float* __restrict__ agg0, float* __restrict__ agg1, float* __restrict__ agg2, int n) {
    __shared__ float a0[CB], a1[CB], a2[CB];
    int t = threadIdx.x;
    a0[t] = 0.f; a1[t] = 0.f; a2[t] = 0.f;
    __syncthreads();
    int b = blockIdx.x / SPL, sl = blockIdx.x % SPL;
    unsigned int s = basec[b], m = cntc[b];
    for (unsigned int i = sl * BT + t; i < m; i += SPL * BT) {
        unsigned rec = tmp[s + i];
        float4 v = xs4[rec >> CB_SHIFT];
        unsigned dl = rec & (CB - 1u);
        atomicAdd(&a0[dl], v.x); atomicAdd(&a1[dl], v.y); atomicAdd(&a2[dl], v.z);
    }
    __syncthreads();
    int node = b * CB + t;
    if (node < n) {
        if (a0[t] != 0.f) atomicAdd(&agg0[node], a0[t]);
        if (a1[t] != 0.f) atomicAdd(&agg1[node], a1[t]);
        if (a2[t] != 0.f) atomicAdd(&agg2[node], a2[t]);
    }
}
__global__ void k_epi_s(const float* __restrict__ agg0, const float* __restrict__ agg1,
                        const float* __restrict__ agg2, const float4* __restrict__ xs4,
                        const float* __restrict__ W1, const float* __restrict__ b1,
                        const float* __restrict__ W2, const float* __restrict__ b2,
                        float* __restrict__ t2s, float* __restrict__ out, int n) {
    int i = blockIdx.x * blockDim.x + threadIdx.x;
    if (i >= n) return;
    float4 xv = xs4[i];
    float iv = xv.w;
    float v0 = iv * (agg0[i] + xv.x), v1 = iv * (agg1[i] + xv.y), v2 = iv * (agg2[i] + xv.z);
    float acc = 0.f;
#pragma unroll
    for (int j = 0; j < HIDDEN; j++) {
        float h = fmaxf(fmaf(v0, W1[j], fmaf(v1, W1[HIDDEN + j],
                       fmaf(v2, W1[2 * HIDDEN + j], b1[j]))), 0.f);
        acc += h * W2[j];
    }
    t2s[i] = acc * iv;
    out[i] = b2[0] + acc * iv * iv;
}
__global__ __launch_bounds__(BT) void
k_s2_split(const unsigned int* __restrict__ tmp, const unsigned int* __restrict__ basec,
           const unsigned int* __restrict__ cntc, const float* __restrict__ t2s,
           const float4* __restrict__ xs4, float* __restrict__ out, int n) {
    __shared__ float o[CB];
    int t = threadIdx.x;
    o[t] = 0.f;
    __syncthreads();
    int b = blockIdx.x / SPL, sl = blockIdx.x % SPL;
    unsigned int s = basec[b], m = cntc[b];
    for (unsigned int i = sl * BT + t; i < m; i += SPL * BT) {
        unsigned rec = tmp[s + i];
        atomicAdd(&o[rec & (CB - 1u)], t2s[rec >> CB_SHIFT]);
    }
    __syncthreads();
    int node = b * CB + t;
    if (node < n && o[t] != 0.f) atomicAdd(&out[node], o[t] * xs4[node].w);
}

// ======================= launch =======================

extern "C" void kernel_launch(void* const* d_in, const int* in_sizes, int n_in,
                              void* d_out, int out_size, void* d_ws, size_t ws_size,
                              hipStream_t stream) {
    const float* x  = (const float*)d_in[0];
    const int*   ei = (const int*)d_in[1];
    const float* W1 = (const float*)d_in[2];
    const float* b1 = (const float*)d_in[3];
    const float* W2 = (const float*)d_in[4];
    const float* b2 = (const float*)d_in[5];
    float* out = (float*)d_out;

    int n = in_sizes[0] / 3;
    int e = in_sizes[1] / 2;
    const int* src = ei;
    const int* dst = ei + e;
    const int B = 256;

    int ncb = (n + CB - 1) / CB;
    int nchunk = (e + CHUNK - 1) / CHUNK;
    int gridN2 = (2 * n + B - 1) / B;

    size_t needc = (size_t)n * 16 + (size_t)n * 4 + (size_t)(n + 1) * 4
                 + (size_t)(2 * ncb + 1) * 4 + (size_t)ncb * nchunk * 4
                 + (size_t)e * 8 + 64;

    if (ncb <= 256 && n < (1 << 21) && ws_size >= needc) {
        float4* xs4 = (float4*)d_ws;                            // n
        float* t2s = (float*)(xs4 + n);                         // n
        unsigned int* rowptr = (unsigned int*)(t2s + n);        // n+1
        unsigned int* cntc   = rowptr + (n + 1);                // ncb
        unsigned int* basec  = cntc + ncb;                      // ncb+1
        unsigned int* hcT    = basec + ncb + 1;                 // ncb*nchunk
        unsigned int* tmp    = hcT + (size_t)ncb * nchunk;      // e
        unsigned int* tmp2   = tmp + e;                         // e

        k_hist<<<nchunk, B, 0, stream>>>(dst, e, ncb, nchunk, hcT);
        k_scanf<<<ncb, B, 0, stream>>>(hcT, cntc, nchunk);
        k_scanb<<<1, B, 0, stream>>>(cntc, ncb, basec, rowptr, n, (unsigned)e);
        k_fill<<<nchunk, B, 0, stream>>>(src, dst, e, ncb, nchunk, basec, hcT, tmp);
        k_cnt<<<ncb, BT, 0, stream>>>(tmp, basec, x, rowptr, xs4, n);
        k_scat<<<ncb * SUBP, BT, 0, stream>>>(tmp, basec, rowptr, tmp2, n);
        k_s1<<<gridN2, B, 0, stream>>>(rowptr, tmp2, xs4, W1, b1, W2, b2, t2s, out, n);
        k_s2<<<gridN2, B, 0, stream>>>(rowptr, tmp2, t2s, xs4, out, n);
    } else {
        int gridN = (n + B - 1) / B;
        float4* xs4 = (float4*)d_ws;
        float* agg0 = (float*)(xs4 + n);
        float* agg1 = agg0 + n;
        float* agg2 = agg1 + n;
        unsigned int* deg = (unsigned int*)(agg2 + n);
        float* t2s = (float*)(deg + n);
        unsigned int* cntc   = (unsigned int*)(t2s + n);
        unsigned int* basec  = cntc + ncb;
        unsigned int* hcT    = basec + ncb + 1;
        unsigned int* tmp    = hcT + (size_t)ncb * nchunk;

        k_zero<<<(4 * n + B - 1) / B, B, 0, stream>>>((unsigned int*)agg0, 4 * n);
        k_hist<<<nchunk, B, 0, stream>>>(dst, e, ncb, nchunk, hcT);
        k_scanf<<<ncb, B, 0, stream>>>(hcT, cntc, nchunk);
        k_scanb<<<1, B, 0, stream>>>(cntc, ncb, basec, (unsigned int*)t2s, 0, (unsigned)e);
        k_fill<<<nchunk, B, 0, stream>>>(src, dst, e, ncb, nchunk, basec, hcT, tmp);
        k_deg_split<<<ncb * SPL, BT, 0, stream>>>(tmp, basec, cntc, deg, n);
        k_inv_s<<<gridN, B, 0, stream>>>(deg, x, xs4, n);
        k_s1_split<<<ncb * SPL, BT, 0, stream>>>(tmp, basec, cntc, xs4, agg0, agg1, agg2, n);
        k_epi_s<<<gridN, B, 0, stream>>>(agg0, agg1, agg2, xs4, W1, b1, W2, b2, t2s, out, n);
        k_s2_split<<<ncb * SPL, BT, 0, stream>>>(tmp, basec, cntc, t2s, xs4, out, n);
    }
}